// Round 8
// baseline (3757.521 us; speedup 1.0000x reference)
//
#include <hip/hip_runtime.h>

// VQBlock: x[16,64,64,256] fp32, dict[256,1024] fp32.
// out = concat(q_st flat [16777216], loss [1]) fp32.
//
// Round 10 = r9 skeleton + T4 counted-vmcnt pipeline (guide §5.5 T3+T4):
//  - r1/r7/r9 all ~240us despite fixing conflicts/VALU/staging-issue order:
//    per-block round = ~18K cycles for ~600 cycles of work. The loop-bottom
//    __syncthreads compiles to s_waitcnt vmcnt(0)+barrier -> staging loads
//    NEVER span a barrier (m233's 2-phase ceiling). Fix = m218's counted
//    vmcnt: triple-buffer LDS, prefetch distance 2, per-chunk
//    {s_waitcnt vmcnt(4); raw s_barrier; sched_barrier(0)} -- vmcnt never 0
//    in the loop (last chunk peeled with vmcnt(0)).
//  - dictnorm moved to LDS (preloaded once): in-loop dn reads are ds_read
//    (lgkmcnt) so they don't pollute the vmcnt counting.
//  - Wave-local rescan/epilogue/loss (absmax-0.0-proven in r5/r6) free up
//    the LDS for 3 buffers: total 52KB -> 3 blocks/CU at launch_bounds(256,3).
//  - Packed-u32 branchless top-2 (absmax 0.0 r5-r9): EPS_TIE 6e-3,
//    dictnorm +8 bias; ambiguous rows -> np-fp32-faithful wave-local rescan.
//  - q_st written as fl(x + fl(q-x)) to match np exactly.

#define NROWS   65536
#define DIM     256
#define NCODE   1024
#define RPB     64                  // rows per block = 4 waves x 16 rows
#define NBLK    (NROWS / RPB)       // 1024
#define NCHUNK  32                  // 32 codes per chunk (16 KB staged)
#define EPS_TIE 6e-3f

typedef _Float16 half8 __attribute__((ext_vector_type(8)));
typedef float    f32x4 __attribute__((ext_vector_type(4)));

// ---------- merged prep kernel (unchanged from r9) ----------
// One coalesced read of dict[e]; scatter-write transpose + f16 MFMA-B pack.
// pack position for dict element (d, k):
//   cc=k>>5, t=(k>>4)&1, l15=k&15, kk=d>>5, q=(d>>3)&3, j=d&7
//   o = cc*8192 + (kk*2+t)*512 + q*128 + l15*8 + j
__global__ void k_prep(const float* __restrict__ dict, float* __restrict__ dictT,
                       float* __restrict__ dictnorm, unsigned short* __restrict__ packB) {
    int gid = blockIdx.x * 256 + threadIdx.x;          // grid 256 x 256
#pragma unroll
    for (int ii = 0; ii < 4; ++ii) {
        int e = ii * 65536 + gid;                      // coalesced read
        const float v = dict[e];
        const int d = e >> 10, k = e & 1023;
        dictT[k * DIM + d] = v;                        // scatter 4B write
        _Float16 h = (_Float16)v;                      // RTN cvt
        const int o = (k >> 5) * 8192 + ((d >> 5) * 2 + ((k >> 4) & 1)) * 512
                    + ((d >> 3) & 3) * 128 + (k & 15) * 8 + (d & 7);
        packB[o] = *(unsigned short*)&h;               // scatter 2B write
    }
    if (blockIdx.x < 4) {
        int k = blockIdx.x * 256 + threadIdx.x;        // coalesced column sums
        float s = 0.f;
#pragma unroll 8
        for (int d = 0; d < DIM; ++d) {
            float v = dict[d * NCODE + k];
            s = fmaf(v, v, s);
        }
        dictnorm[k] = s + 8.0f;    // bias for packed-selection positivity; cancels in gaps
    }
}

// np pairwise sum of squares of 128 contiguous elements
__device__ __forceinline__ float np_pairwise_sq_128(const float* a, int stride) {
    float r[8];
#pragma unroll
    for (int j = 0; j < 8; ++j) {
        float v = a[j * stride];
        r[j] = __fmul_rn(v, v);
    }
    for (int i = 8; i < 128; i += 8) {
#pragma unroll
        for (int j = 0; j < 8; ++j) {
            float v = a[(i + j) * stride];
            r[j] = __fadd_rn(r[j], __fmul_rn(v, v));
        }
    }
    return __fadd_rn(__fadd_rn(__fadd_rn(r[0], r[1]), __fadd_rn(r[2], r[3])),
                     __fadd_rn(__fadd_rn(r[4], r[5]), __fadd_rn(r[6], r[7])));
}

// ---------- main kernel ----------

// Stage chunk cc (16KB) into buffer at bufptr via 4 x global_load_lds, tid-linear.
#define STAGE(bufptr, cc) do {                                                         \
    const unsigned short* _s = packB + (size_t)(cc) * 8192 + tid * 8;                  \
    unsigned short* _d = (bufptr) + tid * 8;                                           \
    _Pragma("unroll")                                                                  \
    for (int _p = 0; _p < 4; ++_p)                                                     \
        __builtin_amdgcn_global_load_lds(                                              \
            (const __attribute__((address_space(1))) unsigned int*)(_s + _p * 2048),   \
            (__attribute__((address_space(3))) unsigned int*)(_d + _p * 2048),         \
            16, 0, 0);                                                                 \
} while (0)

// one chunk's compute: 16 ds_read_b128 + 16 MFMA + packed top-2 select
#define COMPUTE(cc, bs) do {                                                           \
    const int _c0 = (cc) * 32;                                                         \
    float _dn[2];                                                                      \
    _dn[0] = dn_lds[_c0 + l15];                                                        \
    _dn[1] = dn_lds[_c0 + 16 + l15];                                                   \
    const f32x4 _zero = {0.f, 0.f, 0.f, 0.f};                                          \
    f32x4 _acc[2]; _acc[0] = _zero; _acc[1] = _zero;                                   \
    _Pragma("unroll")                                                                  \
    for (int _kk = 0; _kk < 8; ++_kk) {                                                \
        _Pragma("unroll")                                                              \
        for (int _t = 0; _t < 2; ++_t) {                                               \
            const half8 _b = *(const half8*)&(bs)[(_kk * 2 + _t) * 512 + q * 128 + l15 * 8]; \
            _acc[_t] = __builtin_amdgcn_mfma_f32_16x16x32_f16(afrag[_kk], _b, _acc[_t], 0, 0, 0); \
        }                                                                              \
    }                                                                                  \
    _Pragma("unroll")                                                                  \
    for (int _t = 0; _t < 2; ++_t) {                                                   \
        const unsigned _kbase = (unsigned)(_c0 + _t * 16 + l15);                       \
        _Pragma("unroll")                                                              \
        for (int _i = 0; _i < 4; ++_i) {                                               \
            const float _s = fmaf(-2.f, _acc[_t][_i], _dn[_t]);                        \
            const unsigned _pk = (__float_as_uint(_s) & 0xFFFFFC00u) | _kbase;         \
            const unsigned _mx = p1v[_i] > _pk ? p1v[_i] : _pk;                        \
            p2v[_i] = p2v[_i] < _mx ? p2v[_i] : _mx;                                   \
            p1v[_i] = p1v[_i] < _pk ? p1v[_i] : _pk;                                   \
        }                                                                              \
    }                                                                                  \
} while (0)

__global__ __launch_bounds__(256, 3) void k_vq(
    const float* __restrict__ x, const float* __restrict__ dict,
    const float* __restrict__ dictT, const float* __restrict__ dictnorm,
    const unsigned short* __restrict__ packB,
    float* __restrict__ out, double* __restrict__ wave_sums)
{
    __shared__ __align__(16) unsigned short bstage[3][8192];  // 3 x 16 KB ring
    __shared__ float dn_lds[NCODE];                           // 4 KB

    const int tid  = threadIdx.x;
    const int ln   = tid & 63, wv = tid >> 6;
    const int l15  = ln & 15, q = ln >> 4;
    const int row0 = blockIdx.x * RPB;
    const int wrow = row0 + wv * 16;                  // this wave's 16 rows
    const int gwave = blockIdx.x * 4 + wv;

    // dictnorm -> LDS (so in-loop dn reads are lgkmcnt, not vmcnt)
    {
        const float4 v = *(const float4*)&dictnorm[tid * 4];
        *(float4*)&dn_lds[tid * 4] = v;
    }
    __syncthreads();                                  // one-time full barrier

    // start the pipeline: chunks 0 and 1 in flight (8 loads/wave)
    STAGE(&bstage[0][0], 0);
    STAGE(&bstage[1][0], 1);

    // A fragments (register-resident, reused over all 32 chunks)
    half8 afrag[8];
    {
        const float* ar = x + (size_t)(wrow + l15) * DIM + q * 8;
#pragma unroll
        for (int kk = 0; kk < 8; ++kk) {
            const float4 p0 = *(const float4*)(ar + kk * 32);
            const float4 p1 = *(const float4*)(ar + kk * 32 + 4);
            half8 h;
            h[0] = (_Float16)p0.x; h[1] = (_Float16)p0.y; h[2] = (_Float16)p0.z; h[3] = (_Float16)p0.w;
            h[4] = (_Float16)p1.x; h[5] = (_Float16)p1.y; h[6] = (_Float16)p1.z; h[7] = (_Float16)p1.w;
            afrag[kk] = h;
        }
    }

    // packed top-2 per lane for its 4 C-rows (local rows q*4+i)
    unsigned p1v[4], p2v[4];
#pragma unroll
    for (int i = 0; i < 4; ++i) { p1v[i] = 0xFFFFFFFFu; p2v[i] = 0xFFFFFFFFu; }

    // main loop, chunks 0..30: counted vmcnt(4) -- loads span barriers (T4)
    for (int cc = 0; cc < NCHUNK - 1; ++cc) {
        asm volatile("s_waitcnt vmcnt(4)" ::: "memory");  // chunk cc landed (newest 4 = cc+1)
        __builtin_amdgcn_s_barrier();                     // raw: NO drain
        __builtin_amdgcn_sched_barrier(0);                // rule #18 fence
        if (cc + 2 < NCHUNK) STAGE(&bstage[(cc + 2) % 3][0], cc + 2);
        const unsigned short* bs = &bstage[cc % 3][0];
        COMPUTE(cc, bs);
    }
    // peeled last chunk: drain fully (no more prefetch)
    {
        asm volatile("s_waitcnt vmcnt(0)" ::: "memory");
        __builtin_amdgcn_s_barrier();
        __builtin_amdgcn_sched_barrier(0);
        const unsigned short* bs = &bstage[(NCHUNK - 1) % 3][0];
        COMPUTE(NCHUNK - 1, bs);
    }

    // top-2 merge across the 16 lanes sharing quad q; butterfly -> all lanes
    unsigned a1m[4]; float gapm[4];
#pragma unroll
    for (int i = 0; i < 4; ++i) {
        unsigned a1 = p1v[i], a2 = p2v[i];
#pragma unroll
        for (int m = 1; m < 16; m <<= 1) {
            const unsigned o1 = __shfl_xor(a1, m);
            const unsigned o2 = __shfl_xor(a2, m);
            const unsigned mx = a1 > o1 ? a1 : o1;
            a1 = a1 < o1 ? a1 : o1;
            const unsigned mn2 = a2 < o2 ? a2 : o2;
            a2 = mx < mn2 ? mx : mn2;
        }
        a1m[i] = a1;
        gapm[i] = __uint_as_float(a2 & 0xFFFFFC00u) - __uint_as_float(a1 & 0xFFFFFC00u);
    }

    // gather per-row winner + ambiguity mask (wave-uniform). row rr = q*4 + i
    int k1r[16]; unsigned ambmask = 0u;
#pragma unroll
    for (int rr = 0; rr < 16; ++rr) {
        const int src = (rr >> 2) * 16;               // any lane of source quad
        k1r[rr] = __shfl((int)(a1m[rr & 3] & 1023u), src);
        const float g = __shfl(gapm[rr & 3], src);
        ambmask |= (g < EPS_TIE ? 1u : 0u) << rr;
    }

    // np-fp32-faithful full rescan of ambiguous rows (wave-local; proven r5/r6)
    while (ambmask) {
        const int rr = __builtin_ctz(ambmask); ambmask &= ambmask - 1u;
        const float* xr = x + (size_t)(wrow + rr) * DIM;
        const float nf = __fadd_rn(np_pairwise_sq_128(xr, 1), np_pairwise_sq_128(xr + 128, 1));
        float bd = 3.4e38f; int bk = 0x7fffffff;
        for (int c = 0; c < 16; ++c) {
            const int k = c * 64 + ln;                    // coalesced dict reads
            float sim = 0.f, nd = 0.f;
            for (int d = 0; d < DIM; ++d) {
                const float dv = dict[(size_t)d * NCODE + k];
                const float fv = xr[d];                    // broadcast (L1)
                sim = fmaf(fv, dv, sim);                   // BLAS-style FMA chain, d asc
                nd  = __fadd_rn(nd, __fmul_rn(dv, dv));    // np axis-0 reduce
            }
            const float dist = __fsub_rn(__fadd_rn(nf, nd), __fmul_rn(2.f, sim));
            if (dist < bd) { bd = dist; bk = k; }
        }
#pragma unroll
        for (int m = 1; m < 64; m <<= 1) {
            const float od = __shfl_xor(bd, m);
            const int   ok = __shfl_xor(bk, m);
            if (od < bd || (od == bd && ok < bk)) { bd = od; bk = ok; }
        }
        // static-index update of k1r (rule #20)
#pragma unroll
        for (int rr2 = 0; rr2 < 16; ++rr2)
            k1r[rr2] = (rr2 == rr) ? bk : k1r[rr2];
    }

    // epilogue (wave-local): q = 0.5*dictT[kstar]; out = fl(x + fl(q-x)); loss
    float lsum = 0.f;
#pragma unroll
    for (int rr = 0; rr < 16; ++rr) {
        const size_t e = (size_t)(wrow + rr) * DIM + ln * 4;
        const float4 dv = *(const float4*)&dictT[(size_t)k1r[rr] * DIM + ln * 4];
        const float4 xv = *(const float4*)&x[e];
        float4 qv; qv.x = 0.5f * dv.x; qv.y = 0.5f * dv.y; qv.z = 0.5f * dv.z; qv.w = 0.5f * dv.w;
        float4 ov;
        ov.x = __fadd_rn(xv.x, __fsub_rn(qv.x, xv.x));
        ov.y = __fadd_rn(xv.y, __fsub_rn(qv.y, xv.y));
        ov.z = __fadd_rn(xv.z, __fsub_rn(qv.z, xv.z));
        ov.w = __fadd_rn(xv.w, __fsub_rn(qv.w, xv.w));
        const float e0 = __fsub_rn(xv.x, qv.x), e1 = __fsub_rn(xv.y, qv.y);
        const float e2 = __fsub_rn(xv.z, qv.z), e3 = __fsub_rn(xv.w, qv.w);
        lsum += e0 * e0 + e1 * e1 + e2 * e2 + e3 * e3;
        *(float4*)&out[e] = ov;
    }

#pragma unroll
    for (int sft = 32; sft > 0; sft >>= 1) lsum += __shfl_down(lsum, sft, 64);
    if (ln == 0) wave_sums[gwave] = (double)lsum;
}

// ---------- loss finalize ----------

__global__ void k_finalize(const double* __restrict__ wave_sums, float* __restrict__ out_loss) {
    __shared__ double w[16];
    const int t = threadIdx.x;                  // 1024 threads; 4096 wave sums
    double v = wave_sums[t] + wave_sums[t + 1024] + wave_sums[t + 2048] + wave_sums[t + 3072];
#pragma unroll
    for (int sft = 32; sft > 0; sft >>= 1) v += __shfl_down(v, sft, 64);
    if ((t & 63) == 0) w[t >> 6] = v;
    __syncthreads();
    if (t == 0) {
        double tot = 0.0;
        for (int i = 0; i < 16; ++i) tot += w[i];
        out_loss[0] = (float)(1.25 * tot / (double)(NROWS * DIM));
    }
}

// ---------- launch ----------

extern "C" void kernel_launch(void* const* d_in, const int* in_sizes, int n_in,
                              void* d_out, int out_size, void* d_ws, size_t ws_size,
                              hipStream_t stream) {
    (void)in_sizes; (void)n_in; (void)out_size; (void)ws_size;
    const float* x    = (const float*)d_in[0];
    const float* dict = (const float*)d_in[1];
    float* out = (float*)d_out;

    char* ws = (char*)d_ws;
    float*          dictT      = (float*)ws;                          // 1 MB
    float*          dictnorm   = (float*)(ws + 1048576);              // 4 KB
    double*         wave_sums  = (double*)(ws + 1048576 + 4096);      // 32 KB
    unsigned short* packB      = (unsigned short*)(ws + 1048576 + 4096 + 32768); // 512 KB

    k_prep<<<256, 256, 0, stream>>>(dict, dictT, dictnorm, packB);
    k_vq<<<NBLK, 256, 0, stream>>>(x, dict, dictT, dictnorm, packB, out, wave_sums);
    k_finalize<<<1, 1024, 0, stream>>>(wave_sums, out + (size_t)NROWS * DIM);
}

// Round 9
// 324.542 us; speedup vs baseline: 11.5779x; 11.5779x over previous
//
#include <hip/hip_runtime.h>

// VQBlock: x[16,64,64,256] fp32, dict[256,1024] fp32.
// out = concat(q_st flat [16777216], loss [1]) fp32.
//
// Round 11 = r9's proven skeleton (242us; block-wide tail) + UNCONFOUNDED
// T4 counted-vmcnt loop:
//  - r5/r6/r10 forensics: all three 3.7-3.9ms failures share the WAVE-LOCAL
//    tail (k1r[] + while(ambmask)) -> scratch spill (+66MB phantom writes,
//    252B/thread). The counted-vmcnt loop was never cleanly tested. This
//    round: r9's block-wide tail VERBATIM, loop changed to T4 only.
//  - Loop: 3x16KB ring (register-held rotating pointers, no runtime idx),
//    prefetch distance 2, per-iter {s_waitcnt vmcnt(4); raw s_barrier;
//    sched_barrier(0)} -- vmcnt never 0 in-loop; last chunk peeled vmcnt(0).
//  - dictnorm in LDS so in-loop VMEM = exactly the 4 STAGE loads (exact
//    vmcnt counting). Tail arrays overlay bstage[0] after a post-loop
//    __syncthreads: LDS = 53248B -> 3 blocks/CU at launch_bounds(256,3).
//  - Packed-u32 branchless top-2 (absmax 0.0 r5-r10): EPS_TIE 6e-3,
//    dictnorm +8 bias; ambiguous rows -> np-fp32-faithful BLOCK-WIDE rescan.
//  - q_st written as fl(x + fl(q-x)) to match np exactly.

#define NROWS   65536
#define DIM     256
#define NCODE   1024
#define RPB     64                  // rows per block = 4 waves x 16 rows
#define NBLK    (NROWS / RPB)       // 1024
#define NCHUNK  32                  // 32 codes per chunk (16 KB staged)
#define EPS_TIE 6e-3f

typedef _Float16 half8 __attribute__((ext_vector_type(8)));
typedef float    f32x4 __attribute__((ext_vector_type(4)));

// ---------- merged prep kernel (unchanged from r9) ----------
// One coalesced read of dict[e]; scatter-write transpose + f16 MFMA-B pack.
// pack position for dict element (d, k):
//   cc=k>>5, t=(k>>4)&1, l15=k&15, kk=d>>5, q=(d>>3)&3, j=d&7
//   o = cc*8192 + (kk*2+t)*512 + q*128 + l15*8 + j
__global__ void k_prep(const float* __restrict__ dict, float* __restrict__ dictT,
                       float* __restrict__ dictnorm, unsigned short* __restrict__ packB) {
    int gid = blockIdx.x * 256 + threadIdx.x;          // grid 256 x 256
#pragma unroll
    for (int ii = 0; ii < 4; ++ii) {
        int e = ii * 65536 + gid;                      // coalesced read
        const float v = dict[e];
        const int d = e >> 10, k = e & 1023;
        dictT[k * DIM + d] = v;                        // scatter 4B write
        _Float16 h = (_Float16)v;                      // RTN cvt
        const int o = (k >> 5) * 8192 + ((d >> 5) * 2 + ((k >> 4) & 1)) * 512
                    + ((d >> 3) & 3) * 128 + (k & 15) * 8 + (d & 7);
        packB[o] = *(unsigned short*)&h;               // scatter 2B write
    }
    if (blockIdx.x < 4) {
        int k = blockIdx.x * 256 + threadIdx.x;        // coalesced column sums
        float s = 0.f;
#pragma unroll 8
        for (int d = 0; d < DIM; ++d) {
            float v = dict[d * NCODE + k];
            s = fmaf(v, v, s);
        }
        dictnorm[k] = s + 8.0f;    // bias for packed-selection positivity; cancels in gaps
    }
}

// np pairwise sum of squares of 128 contiguous elements
__device__ __forceinline__ float np_pairwise_sq_128(const float* a, int stride) {
    float r[8];
#pragma unroll
    for (int j = 0; j < 8; ++j) {
        float v = a[j * stride];
        r[j] = __fmul_rn(v, v);
    }
    for (int i = 8; i < 128; i += 8) {
#pragma unroll
        for (int j = 0; j < 8; ++j) {
            float v = a[(i + j) * stride];
            r[j] = __fadd_rn(r[j], __fmul_rn(v, v));
        }
    }
    return __fadd_rn(__fadd_rn(__fadd_rn(r[0], r[1]), __fadd_rn(r[2], r[3])),
                     __fadd_rn(__fadd_rn(r[4], r[5]), __fadd_rn(r[6], r[7])));
}

// ---------- main kernel ----------

// Stage chunk cc (16KB) into buffer at bufptr via 4 x global_load_lds, tid-linear.
#define STAGE(bufptr, cc) do {                                                         \
    const unsigned short* _s = packB + (size_t)(cc) * 8192 + tid * 8;                  \
    unsigned short* _d = (bufptr) + tid * 8;                                           \
    _Pragma("unroll")                                                                  \
    for (int _p = 0; _p < 4; ++_p)                                                     \
        __builtin_amdgcn_global_load_lds(                                              \
            (const __attribute__((address_space(1))) unsigned int*)(_s + _p * 2048),   \
            (__attribute__((address_space(3))) unsigned int*)(_d + _p * 2048),         \
            16, 0, 0);                                                                 \
} while (0)

// one chunk's compute: 16 ds_read_b128 + 16 MFMA + packed top-2 select
#define COMPUTE(cc, bs) do {                                                           \
    const int _c0 = (cc) * 32;                                                         \
    float _dn[2];                                                                      \
    _dn[0] = dn_lds[_c0 + l15];                                                        \
    _dn[1] = dn_lds[_c0 + 16 + l15];                                                   \
    const f32x4 _zero = {0.f, 0.f, 0.f, 0.f};                                          \
    f32x4 _acc[2]; _acc[0] = _zero; _acc[1] = _zero;                                   \
    _Pragma("unroll")                                                                  \
    for (int _kk = 0; _kk < 8; ++_kk) {                                                \
        _Pragma("unroll")                                                              \
        for (int _t = 0; _t < 2; ++_t) {                                               \
            const half8 _b = *(const half8*)&(bs)[(_kk * 2 + _t) * 512 + q * 128 + l15 * 8]; \
            _acc[_t] = __builtin_amdgcn_mfma_f32_16x16x32_f16(afrag[_kk], _b, _acc[_t], 0, 0, 0); \
        }                                                                              \
    }                                                                                  \
    _Pragma("unroll")                                                                  \
    for (int _t = 0; _t < 2; ++_t) {                                                   \
        const unsigned _kbase = (unsigned)(_c0 + _t * 16 + l15);                       \
        _Pragma("unroll")                                                              \
        for (int _i = 0; _i < 4; ++_i) {                                               \
            const float _s = fmaf(-2.f, _acc[_t][_i], _dn[_t]);                        \
            const unsigned _pk = (__float_as_uint(_s) & 0xFFFFFC00u) | _kbase;         \
            const unsigned _mx = p1v[_i] > _pk ? p1v[_i] : _pk;                        \
            p2v[_i] = p2v[_i] < _mx ? p2v[_i] : _mx;                                   \
            p1v[_i] = p1v[_i] < _pk ? p1v[_i] : _pk;                                   \
        }                                                                              \
    }                                                                                  \
} while (0)

__global__ __launch_bounds__(256, 3) void k_vq(
    const float* __restrict__ x, const float* __restrict__ dict,
    const float* __restrict__ dictT, const float* __restrict__ dictnorm,
    const unsigned short* __restrict__ packB,
    float* __restrict__ out, double* __restrict__ block_sums)
{
    __shared__ __align__(16) unsigned short bstage[3][8192];  // 48 KB ring
    __shared__ float dn_lds[NCODE];                           // 4 KB
    // tail arrays overlay bstage[0] (used only after the post-loop barrier):
    float* red_d    = (float*)&bstage[0][0];      // 1 KB (256 f32)
    int*   red_k    = (int*)  &bstage[0][512];    // 1 KB (256 i32)
    float* row_gap  = (float*)&bstage[0][1024];   // 256 B
    int*   row_k1   = (int*)  &bstage[0][1152];   // 256 B
    float* wred     = (float*)&bstage[0][1280];   // 16 B
    int*   amb_list = (int*)  &bstage[0][1288];   // 256 B
    int*   amb_cnt  = (int*)  &bstage[0][1416];   // 4 B

    const int tid  = threadIdx.x;
    const int ln   = tid & 63, wv = tid >> 6;
    const int l15  = ln & 15, q = ln >> 4;
    const int row0 = blockIdx.x * RPB;

    // dictnorm -> LDS (so in-loop dn reads are lgkmcnt, not vmcnt)
    {
        const float4 v = *(const float4*)&dictnorm[tid * 4];
        *(float4*)&dn_lds[tid * 4] = v;
    }
    __syncthreads();                                  // full drain: vmcnt starts at 0

    // A fragments first (their loads retire via the cvt waits below)
    half8 afrag[8];
    {
        const float* ar = x + (size_t)(row0 + wv * 16 + l15) * DIM + q * 8;
#pragma unroll
        for (int kk = 0; kk < 8; ++kk) {
            const float4 p0 = *(const float4*)(ar + kk * 32);
            const float4 p1 = *(const float4*)(ar + kk * 32 + 4);
            half8 h;
            h[0] = (_Float16)p0.x; h[1] = (_Float16)p0.y; h[2] = (_Float16)p0.z; h[3] = (_Float16)p0.w;
            h[4] = (_Float16)p1.x; h[5] = (_Float16)p1.y; h[6] = (_Float16)p1.z; h[7] = (_Float16)p1.w;
            afrag[kk] = h;
        }
    }

    // packed top-2 per lane for its 4 C-rows (local rows q*4+i)
    unsigned p1v[4], p2v[4];
#pragma unroll
    for (int i = 0; i < 4; ++i) { p1v[i] = 0xFFFFFFFFu; p2v[i] = 0xFFFFFFFFu; }

    // pipeline prologue: chunks 0,1 in flight (8 loads/wave outstanding)
    unsigned short* bA = &bstage[0][0];   // holds chunk cc   (read this iter)
    unsigned short* bB = &bstage[1][0];   // holds chunk cc+1
    unsigned short* bC = &bstage[2][0];   // free -> stage chunk cc+2
    STAGE(bA, 0);
    STAGE(bB, 1);
    __builtin_amdgcn_sched_barrier(0);

    // main loop, chunks 0..30: counted vmcnt(4) -- loads span barriers (T4)
    for (int cc = 0; cc < NCHUNK - 1; ++cc) {
        asm volatile("s_waitcnt vmcnt(4)" ::: "memory");  // oldest 4 (= chunk cc) landed
        __builtin_amdgcn_s_barrier();                     // raw: NO drain
        __builtin_amdgcn_sched_barrier(0);                // rule #18 fence
        if (cc + 2 < NCHUNK) STAGE(bC, cc + 2);           // bC free: all waves done with it
        COMPUTE(cc, bA);
        unsigned short* tmp = bA; bA = bB; bB = bC; bC = tmp;   // rotate ring
    }
    // peeled last chunk: drain fully (no more prefetch)
    {
        asm volatile("s_waitcnt vmcnt(0)" ::: "memory");
        __builtin_amdgcn_s_barrier();
        __builtin_amdgcn_sched_barrier(0);
        COMPUTE(NCHUNK - 1, bA);
    }
    __syncthreads();   // all waves done with bstage -> tail arrays may overlay it
    if (tid == 0) *amb_cnt = 0;

    // top-2 merge across the 16 lanes sharing quad q (they hold the same 4 rows)
#pragma unroll
    for (int i = 0; i < 4; ++i) {
        unsigned a1 = p1v[i], a2 = p2v[i];
#pragma unroll
        for (int m = 1; m < 16; m <<= 1) {
            const unsigned o1 = __shfl_xor(a1, m);
            const unsigned o2 = __shfl_xor(a2, m);
            const unsigned mx = a1 > o1 ? a1 : o1;
            a1 = a1 < o1 ? a1 : o1;
            const unsigned mn2 = a2 < o2 ? a2 : o2;
            a2 = mx < mn2 ? mx : mn2;
        }
        if (l15 == 0) {
            const int r = wv * 16 + q * 4 + i;
            row_k1[r]  = (int)(a1 & 1023u);
            row_gap[r] = __uint_as_float(a2 & 0xFFFFFC00u) - __uint_as_float(a1 & 0xFFFFFC00u);
        }
    }
    __syncthreads();

    if (tid < RPB && row_gap[tid] < EPS_TIE) {
        int p = atomicAdd(amb_cnt, 1);
        amb_list[p] = tid;
    }
    __syncthreads();
    const int namb = *amb_cnt;

    // np-fp32-faithful full rescan of ambiguous rows (proven; unchanged)
    for (int a = 0; a < namb; ++a) {
        const int r = amb_list[a];
        const float* xr = x + (size_t)(row0 + r) * DIM;
        const float nf = __fadd_rn(np_pairwise_sq_128(xr, 1), np_pairwise_sq_128(xr + 128, 1));
        float bd = 3.4e38f; int bk = 0x7fffffff;
#pragma unroll
        for (int i = 0; i < 4; ++i) {
            const int k = i * 256 + tid;                  // coalesced dict reads
            float sim = 0.f, nd = 0.f;
            for (int d = 0; d < DIM; ++d) {
                const float dv = dict[(size_t)d * NCODE + k];
                const float fv = xr[d];                    // broadcast (L1)
                sim = fmaf(fv, dv, sim);                   // BLAS-style FMA chain, d asc
                nd  = __fadd_rn(nd, __fmul_rn(dv, dv));    // np axis-0 reduce
            }
            const float dist = __fsub_rn(__fadd_rn(nf, nd), __fmul_rn(2.f, sim));
            if (dist < bd) { bd = dist; bk = k; }
        }
        red_d[tid] = bd; red_k[tid] = bk;
        __syncthreads();
        for (int s = 128; s > 0; s >>= 1) {
            if (tid < s) {
                const float od = red_d[tid + s]; const int ok = red_k[tid + s];
                if (od < red_d[tid] || (od == red_d[tid] && ok < red_k[tid])) {
                    red_d[tid] = od; red_k[tid] = ok;
                }
            }
            __syncthreads();
        }
        if (tid == 0) row_k1[r] = red_k[0];
        __syncthreads();
    }

    // epilogue: q = 0.5*dictT[kstar]; out = fl(x + fl(q-x)) (np-exact); loss partial
    float lsum = 0.f;
#pragma unroll 2
    for (int i = 0; i < 16; ++i) {
        const int e = i * 1024 + tid * 4;
        const int r = e >> 8, d0 = e & 255;
        const int kk = row_k1[r];
        const float4 dv = *(const float4*)&dictT[(size_t)kk * DIM + d0];
        const float4 xv = *(const float4*)&x[(size_t)row0 * DIM + e];
        float4 qv; qv.x = 0.5f * dv.x; qv.y = 0.5f * dv.y; qv.z = 0.5f * dv.z; qv.w = 0.5f * dv.w;
        float4 ov;
        ov.x = __fadd_rn(xv.x, __fsub_rn(qv.x, xv.x));
        ov.y = __fadd_rn(xv.y, __fsub_rn(qv.y, xv.y));
        ov.z = __fadd_rn(xv.z, __fsub_rn(qv.z, xv.z));
        ov.w = __fadd_rn(xv.w, __fsub_rn(qv.w, xv.w));
        const float e0 = __fsub_rn(xv.x, qv.x), e1 = __fsub_rn(xv.y, qv.y);
        const float e2 = __fsub_rn(xv.z, qv.z), e3 = __fsub_rn(xv.w, qv.w);
        lsum += e0 * e0 + e1 * e1 + e2 * e2 + e3 * e3;
        *(float4*)&out[(size_t)row0 * DIM + e] = ov;
    }

#pragma unroll
    for (int sft = 32; sft > 0; sft >>= 1) lsum += __shfl_down(lsum, sft, 64);
    if ((tid & 63) == 0) wred[tid >> 6] = lsum;
    __syncthreads();
    if (tid == 0)
        block_sums[blockIdx.x] = (double)((wred[0] + wred[1]) + (wred[2] + wred[3]));
}

// ---------- loss finalize ----------

__global__ void k_finalize(const double* __restrict__ block_sums, float* __restrict__ out_loss) {
    __shared__ double w[16];
    const int t = threadIdx.x;                  // 1024 threads
    double v = block_sums[t];
#pragma unroll
    for (int sft = 32; sft > 0; sft >>= 1) v += __shfl_down(v, sft, 64);
    if ((t & 63) == 0) w[t >> 6] = v;
    __syncthreads();
    if (t == 0) {
        double tot = 0.0;
        for (int i = 0; i < 16; ++i) tot += w[i];
        out_loss[0] = (float)(1.25 * tot / (double)(NROWS * DIM));
    }
}

// ---------- launch ----------

extern "C" void kernel_launch(void* const* d_in, const int* in_sizes, int n_in,
                              void* d_out, int out_size, void* d_ws, size_t ws_size,
                              hipStream_t stream) {
    (void)in_sizes; (void)n_in; (void)out_size; (void)ws_size;
    const float* x    = (const float*)d_in[0];
    const float* dict = (const float*)d_in[1];
    float* out = (float*)d_out;

    char* ws = (char*)d_ws;
    float*          dictT      = (float*)ws;                          // 1 MB
    float*          dictnorm   = (float*)(ws + 1048576);              // 4 KB
    double*         block_sums = (double*)(ws + 1048576 + 4096);      // 8 KB
    unsigned short* packB      = (unsigned short*)(ws + 1048576 + 4096 + 8192); // 512 KB

    k_prep<<<256, 256, 0, stream>>>(dict, dictT, dictnorm, packB);
    k_vq<<<NBLK, 256, 0, stream>>>(x, dict, dictT, dictnorm, packB, out, block_sums);
    k_finalize<<<1, 1024, 0, stream>>>(block_sums, out + (size_t)NROWS * DIM);
}